// Round 2
// baseline (222.125 us; speedup 1.0000x reference)
//
#include <hip/hip_runtime.h>

#define B_ 4
#define T_ 4096
#define I_ 512
#define E_ 16
#define K_ 1024
#define J_ 512

typedef unsigned short u16;
typedef unsigned int u32;
typedef __attribute__((ext_vector_type(4))) float floatx4;
typedef __attribute__((ext_vector_type(8))) short short8;
typedef __attribute__((ext_vector_type(4))) u16 u16x4;
typedef __attribute__((ext_vector_type(8))) u16 u16x8;

__device__ __forceinline__ u16 f2bf(float f) {
  unsigned int u = __float_as_uint(f);
  u += 0x7FFFu + ((u >> 16) & 1u);   // round-to-nearest-even
  return (u16)(u >> 16);
}

// async global->LDS, 16B per lane, dest = wave-uniform base + lane*16
__device__ __forceinline__ void gload16(const u16* g, u16* l) {
  __builtin_amdgcn_global_load_lds(
      (const __attribute__((address_space(1))) unsigned int*)(g),
      (__attribute__((address_space(3))) unsigned int*)(l),
      16, 0, 0);
}

// ---- prep (merged): blocks [0,1024) transpose W -> Wt bf16;
//                     blocks [1024,3072) convert X -> Xb bf16 ----------------
__global__ __launch_bounds__(256) void prep(const float* __restrict__ X,
                                            const float* __restrict__ W,
                                            u16* __restrict__ Xb,
                                            u16* __restrict__ Wt) {
  const int tid = threadIdx.x;
  const int blk = blockIdx.x;
  if (blk < 1024) {
    // W[e][i][j] fp32 -> Wt[e][j][i] bf16, 64x64 tiles
    __shared__ u16 tile[64][65];
    const int e  = blk >> 6;
    const int bi = (blk >> 3) & 7;
    const int bj = blk & 7;
    const int i0 = bi * 64, j0 = bj * 64;
#pragma unroll
    for (int p = 0; p < 4; ++p) {
      int r = p * 16 + (tid >> 4);
      int c = (tid & 15) * 4;
      floatx4 v = *(const floatx4*)(W + ((size_t)(e * I_ + i0 + r)) * J_ + j0 + c);
      tile[r][c + 0] = f2bf(v[0]);
      tile[r][c + 1] = f2bf(v[1]);
      tile[r][c + 2] = f2bf(v[2]);
      tile[r][c + 3] = f2bf(v[3]);
    }
    __syncthreads();
#pragma unroll
    for (int p = 0; p < 2; ++p) {
      int j = p * 32 + (tid >> 3);
      int ch = tid & 7;
      u16x8 o;
#pragma unroll
      for (int s = 0; s < 8; ++s) o[s] = tile[ch * 8 + s][j];
      *(u16x8*)(Wt + ((size_t)(e * J_ + j0 + j)) * I_ + i0 + ch * 8) = o;
    }
  } else {
    const int n4 = B_ * T_ * I_ / 4;
    int i = (blk - 1024) * 256 + tid;
    const int stride = 2048 * 256;
    for (; i < n4; i += stride) {
      floatx4 v = ((const floatx4*)X)[i];
      u16x4 o;
      o[0] = f2bf(v[0]); o[1] = f2bf(v[1]); o[2] = f2bf(v[2]); o[3] = f2bf(v[3]);
      ((u16x4*)Xb)[i] = o;
    }
  }
}

// ---- main: gather + bf16 MFMA GEMM ----------------------------------------
// Round-0 geometry (256K x 128J tile, 4 waves 2x2, wave-tile 128K x 64J,
// acc 4(j) x 8(k), BK=64) but:
//  * B-operand (Wt) is NOT staged in LDS: wf fragments are read directly
//    from global (L2-resident, 64B-granule pattern: 4 quads x contiguous
//    16B per row), register-double-buffered one K-step ahead.
//  * A (gathered rows) stays in LDS, now double-buffered (2 x 32 KB) in the
//    space B vacated; next tile's gload16 issue before the MFMA section so
//    the end-of-step vmcnt(0) drain lands ~600cy after issue.
//  LDS traffic/wave/K-step: 16KB read + 8KB write for 64 MFMA (43 FLOP/B,
//  under the ~85 B/cy ceiling) vs 36KB before (LDS-BW-bound).
//  XCD-chunked blockIdx swizzle co-locates the 16 blocks sharing one e on
//  one XCD's L2 (Wt panel reuse).
__global__ __launch_bounds__(256, 2) void gemm_gather(
    const u16* __restrict__ Xb, const u16* __restrict__ Wt,
    const int* __restrict__ ind, float* __restrict__ Y) {
  __shared__ alignas(16) u16 Asf[2][256 * 64];   // gathered X rows: 2 x 32 KB

  const int tid = threadIdx.x;
  // XCD swizzle: grid 1024 = 8 XCDs x 128; semantic-adjacent blocks (which
  // share e / Wt panel) land on the same XCD.
  const int blk = ((int)blockIdx.x & 7) * 128 + ((int)blockIdx.x >> 3);
  const int m_t = blk & 3;             // K tile
  const int n_t = (blk >> 2) & 3;      // J tile
  const int be  = blk >> 4;            // b*E + e
  const int e = be & 15;
  const int b = be >> 4;

  const int lane = tid & 63;
  const int wave = tid >> 6;

  // staging mapping: one gload16 covers 8 rows x 8 chunks (16B each)
  const int lr = lane >> 3;                  // row within octet
  const int cg = (lane & 7) ^ lr;            // global chunk for this lane

  // A: 64 gathered rows per wave (8 instrs); 32-bit element offsets
  u32 aoff[8];
#pragma unroll
  for (int q = 0; q < 8; ++q) {
    const int r = wave * 64 + q * 8 + lr;
    const int t = ind[be * K_ + m_t * 256 + r];
    aoff[q] = (u32)(b * T_ + t) * I_ + cg * 8;
  }

  const int wj = (wave & 1) * 64;      // J offset of wave-tile
  const int wk = (wave >> 1) * 128;    // K offset of wave-tile
  const int ml = lane & 15;
  const int quad = lane >> 4;

  // B fragment base: row = n_t*128 + wj + ml (+i*16), chunk = quad (+s*4)
  const u16* __restrict__ wbase =
      Wt + ((size_t)(e * J_ + n_t * 128 + wj + ml)) * I_ + quad * 8;

  floatx4 acc[4][8] = {};              // [iw = J blocks][ik = K blocks]
  short8 wfA[8], wfB[8];               // register-dbuf'd B fragments

  // ---- prologue: wf(it=0) into wfA, A tile0 into Asf[0] ----
#pragma unroll
  for (int i = 0; i < 4; ++i) {
    wfA[i]     = *(const short8*)(wbase + i * 16 * I_);
    wfA[4 + i] = *(const short8*)(wbase + i * 16 * I_ + 32);
  }
  {
    u16* ald = &Asf[0][wave * 4096];
#pragma unroll
    for (int q = 0; q < 8; ++q) gload16(Xb + aoff[q], ald + q * 512);
  }
  asm volatile("s_waitcnt vmcnt(0)" ::: "memory");
  __builtin_amdgcn_s_barrier();

#define GSTEP(IT, CURBUF, WCUR, WNXT)                                          \
  {                                                                            \
    constexpr int kk = (IT) * 64;                                              \
    if ((IT) < 7) {                                                            \
      u16* ald = &Asf[(CURBUF) ^ 1][wave * 4096];                              \
      _Pragma("unroll")                                                        \
      for (int q = 0; q < 8; ++q)                                              \
        gload16(Xb + aoff[q] + kk + 64, ald + q * 512);                        \
      _Pragma("unroll")                                                        \
      for (int i = 0; i < 4; ++i) {                                            \
        WNXT[i]     = *(const short8*)(wbase + i * 16 * I_ + kk + 64);         \
        WNXT[4 + i] = *(const short8*)(wbase + i * 16 * I_ + 32 + kk + 64);    \
      }                                                                        \
    }                                                                          \
    _Pragma("unroll")                                                          \
    for (int s = 0; s < 2; ++s) {                                              \
      const int c = s * 4 + quad;                                              \
      _Pragma("unroll")                                                        \
      for (int ik = 0; ik < 8; ++ik) {                                         \
        const int kr = wk + ik * 16 + ml;                                      \
        const short8 xf =                                                      \
            *(const short8*)&Asf[CURBUF][kr * 64 + ((c ^ (kr & 7)) * 8)];      \
        _Pragma("unroll")                                                      \
        for (int iw = 0; iw < 4; ++iw)                                         \
          acc[iw][ik] = __builtin_amdgcn_mfma_f32_16x16x32_bf16(               \
              WCUR[s * 4 + iw], xf, acc[iw][ik], 0, 0, 0);                     \
      }                                                                        \
    }                                                                          \
    asm volatile("s_waitcnt vmcnt(0)" ::: "memory");                           \
    __builtin_amdgcn_s_barrier();                                              \
  }

  GSTEP(0, 0, wfA, wfB)
  GSTEP(1, 1, wfB, wfA)
  GSTEP(2, 0, wfA, wfB)
  GSTEP(3, 1, wfB, wfA)
  GSTEP(4, 0, wfA, wfB)
  GSTEP(5, 1, wfB, wfA)
  GSTEP(6, 0, wfA, wfB)
  GSTEP(7, 1, wfB, wfA)
#undef GSTEP

  // epilogue: D row (m) = j = quad*4 + reg -> one float4 per tile
#pragma unroll
  for (int iw = 0; iw < 4; ++iw) {
    const int j0 = n_t * 128 + wj + iw * 16 + quad * 4;
#pragma unroll
    for (int ik = 0; ik < 8; ++ik) {
      const int k0 = m_t * 256 + wk + ik * 16 + ml;
      *(floatx4*)(Y + ((size_t)(be * K_ + k0)) * J_ + j0) = acc[iw][ik];
    }
  }
}

extern "C" void kernel_launch(void* const* d_in, const int* in_sizes, int n_in,
                              void* d_out, int out_size, void* d_ws,
                              size_t ws_size, hipStream_t stream) {
  const float* X  = (const float*)d_in[0];
  const int* ind  = (const int*)d_in[1];
  const float* W  = (const float*)d_in[2];
  float* Y = (float*)d_out;

  u16* Xb = (u16*)d_ws;                                        // 16 MiB
  u16* Wt = (u16*)((char*)d_ws + (size_t)B_ * T_ * I_ * 2);    // + 8 MiB

  prep<<<3072, 256, 0, stream>>>(X, W, Xb, Wt);
  gemm_gather<<<1024, 256, 0, stream>>>(Xb, Wt, ind, Y);
}

// Round 3
// 203.483 us; speedup vs baseline: 1.0916x; 1.0916x over previous
//
#include <hip/hip_runtime.h>

#define B_ 4
#define T_ 4096
#define I_ 512
#define E_ 16
#define K_ 1024
#define J_ 512

typedef unsigned short u16;
typedef unsigned int u32;
typedef __attribute__((ext_vector_type(4))) float floatx4;
typedef __attribute__((ext_vector_type(8))) short short8;
typedef __attribute__((ext_vector_type(4))) u16 u16x4;
typedef __attribute__((ext_vector_type(8))) u16 u16x8;

__device__ __forceinline__ u16 f2bf(float f) {
  unsigned int u = __float_as_uint(f);
  u += 0x7FFFu + ((u >> 16) & 1u);   // round-to-nearest-even
  return (u16)(u >> 16);
}

// async global->LDS, 16B per lane, dest = wave-uniform base + lane*16
__device__ __forceinline__ void gload16(const u16* g, u16* l) {
  __builtin_amdgcn_global_load_lds(
      (const __attribute__((address_space(1))) unsigned int*)(g),
      (__attribute__((address_space(3))) unsigned int*)(l),
      16, 0, 0);
}

// ---- prep (merged): blocks [0,1024) transpose W -> Wt bf16;
//                     blocks [1024,3072) convert X -> Xb bf16 ----------------
__global__ __launch_bounds__(256) void prep(const float* __restrict__ X,
                                            const float* __restrict__ W,
                                            u16* __restrict__ Xb,
                                            u16* __restrict__ Wt) {
  const int tid = threadIdx.x;
  const int blk = blockIdx.x;
  if (blk < 1024) {
    // W[e][i][j] fp32 -> Wt[e][j][i] bf16, 64x64 tiles
    __shared__ u16 tile[64][65];
    const int e  = blk >> 6;
    const int bi = (blk >> 3) & 7;
    const int bj = blk & 7;
    const int i0 = bi * 64, j0 = bj * 64;
#pragma unroll
    for (int p = 0; p < 4; ++p) {
      int r = p * 16 + (tid >> 4);
      int c = (tid & 15) * 4;
      floatx4 v = *(const floatx4*)(W + ((size_t)(e * I_ + i0 + r)) * J_ + j0 + c);
      tile[r][c + 0] = f2bf(v[0]);
      tile[r][c + 1] = f2bf(v[1]);
      tile[r][c + 2] = f2bf(v[2]);
      tile[r][c + 3] = f2bf(v[3]);
    }
    __syncthreads();
#pragma unroll
    for (int p = 0; p < 2; ++p) {
      int j = p * 32 + (tid >> 3);
      int ch = tid & 7;
      u16x8 o;
#pragma unroll
      for (int s = 0; s < 8; ++s) o[s] = tile[ch * 8 + s][j];
      *(u16x8*)(Wt + ((size_t)(e * J_ + j0 + j)) * I_ + i0 + ch * 8) = o;
    }
  } else {
    const int n4 = B_ * T_ * I_ / 4;
    int i = (blk - 1024) * 256 + tid;
    const int stride = 2048 * 256;
    for (; i < n4; i += stride) {
      floatx4 v = ((const floatx4*)X)[i];
      u16x4 o;
      o[0] = f2bf(v[0]); o[1] = f2bf(v[1]); o[2] = f2bf(v[2]); o[3] = f2bf(v[3]);
      ((u16x4*)Xb)[i] = o;
    }
  }
}

// ---- main: gather + bf16 MFMA GEMM -----------------------------------------
// Round-0 geometry: per block 256 K-rows x 128 J-cols of one (b,e); 4 waves
// as 2x2 of 128K x 64J wave-tiles; acc 4(j) x 8(k); BK=64, 8 K-steps.
// Pipeline change (keeps 2 blocks/CU, unlike the 128KB dbuf attempt):
//   * A (gathered rows, the latency-critical operand) double-buffered:
//     2 x 32KB; B (Wt, contiguous L2-hot) single 16KB -> 80KB = 160/2 exactly.
//   * Per step: compute(A[cur],B) ; barrier ; issue B(it+1) [4 contig loads] ;
//     issue A(it+2) into freed buffer [8 gathers] ; s_waitcnt vmcnt(8)
//     (= B(it+1)+A(it+1) done, A(it+2) still flying) ; barrier.
//   Exposed per-step latency drops from 8 fresh random gathers (round 0's
//   __syncthreads drain) to 4 contiguous Wt loads; gathers get a full
//   compute-step (~600cy) of cover.
// XCD-chunked swizzle: chunk=128 consecutive blk per XCD -> per-XCD working
// set = Xb[b] (4MB) + 8 Wt panels, vs 24MB round-robin.
// MFMA roles: A-op = Wt rows (M=J), B-op = gathered X rows (N=K) so D rows
// are consecutive j -> dwordx4 stores. XOR chunk swizzle c_lds = c ^ (row&7).
__global__ __launch_bounds__(256, 2) void gemm_gather(
    const u16* __restrict__ Xb, const u16* __restrict__ Wt,
    const int* __restrict__ ind, float* __restrict__ Y) {
  __shared__ alignas(16) u16 Asf[2][256 * 64];   // gathered X rows: 2 x 32 KB
  __shared__ alignas(16) u16 Bsf[128 * 64];      // Wt rows:             16 KB

  const int tid = threadIdx.x;
  // XCD swizzle: grid 1024 = 8 XCDs x 128-chunk; blocks sharing b (and e
  // groups) land on the same XCD's L2.
  const int blk = ((int)blockIdx.x & 7) * 128 + ((int)blockIdx.x >> 3);
  const int m_t = blk & 3;             // K tile
  const int n_t = (blk >> 2) & 3;      // J tile
  const int be  = blk >> 4;            // b*E + e
  const int e = be & 15;
  const int b = be >> 4;

  const int lane = tid & 63;
  const int wave = tid >> 6;

  // staging mapping: one gload16 covers 8 rows x 8 chunks (16B each)
  const int lr = lane >> 3;                  // row within octet
  const int cg = (lane & 7) ^ lr;            // global chunk for this lane

  // A: 64 gathered rows per wave (8 instrs); keep 32-bit element offsets
  u32 aoff[8];
#pragma unroll
  for (int q = 0; q < 8; ++q) {
    const int r = wave * 64 + q * 8 + lr;
    const int t = ind[be * K_ + m_t * 256 + r];
    aoff[q] = (u32)(b * T_ + t) * I_ + cg * 8;
  }
  // B: 32 rows per wave (4 instrs), contiguous base
  const u16* bbase =
      Wt + ((size_t)(e * J_ + n_t * 128 + wave * 32 + lr)) * I_ + cg * 8;
  u16* bld = Bsf + (wave * 32) * 64;

  const int wj = (wave & 1) * 64;      // J offset of wave-tile
  const int wk = (wave >> 1) * 128;    // K offset of wave-tile
  const int ml = lane & 15;
  const int quad = lane >> 4;

  floatx4 acc[4][8] = {};              // [iw = J blocks][ik = K blocks]

  // ---- prologue: B(0), A(0) into buf0, A(1) into buf1; wait all but A(1) --
#pragma unroll
  for (int q = 0; q < 4; ++q) gload16(bbase + q * 8 * I_, bld + q * 512);
  {
    u16* a0 = &Asf[0][wave * 4096];
#pragma unroll
    for (int q = 0; q < 8; ++q) gload16(Xb + aoff[q], a0 + q * 512);
    u16* a1 = &Asf[1][wave * 4096];
#pragma unroll
    for (int q = 0; q < 8; ++q) gload16(Xb + aoff[q] + 64, a1 + q * 512);
  }
  asm volatile("s_waitcnt vmcnt(8)" ::: "memory");   // B0 + A0 done
  __builtin_amdgcn_s_barrier();

#define GSTEP(IT)                                                              \
  {                                                                            \
    constexpr int cur = (IT) & 1;                                              \
    _Pragma("unroll")                                                          \
    for (int s = 0; s < 2; ++s) {      /* two K=32 sub-steps */                \
      const int c = s * 4 + quad;                                              \
      short8 wf[4];                                                            \
      _Pragma("unroll")                                                        \
      for (int i = 0; i < 4; ++i) {                                            \
        const int jr = wj + i * 16 + ml;                                       \
        wf[i] = *(const short8*)&Bsf[jr * 64 + ((c ^ (jr & 7)) * 8)];          \
      }                                                                        \
      _Pragma("unroll")                                                        \
      for (int ik = 0; ik < 8; ++ik) {                                         \
        const int kr = wk + ik * 16 + ml;                                      \
        const short8 xf =                                                      \
            *(const short8*)&Asf[cur][kr * 64 + ((c ^ (kr & 7)) * 8)];         \
        _Pragma("unroll")                                                      \
        for (int iw = 0; iw < 4; ++iw)                                         \
          acc[iw][ik] = __builtin_amdgcn_mfma_f32_16x16x32_bf16(               \
              wf[iw], xf, acc[iw][ik], 0, 0, 0);                               \
      }                                                                        \
    }                                                                          \
    if ((IT) < 7) {                                                            \
      __builtin_amdgcn_s_barrier();    /* all waves done reading Bsf/A[cur] */ \
      _Pragma("unroll")                                                        \
      for (int q = 0; q < 4; ++q)      /* B(it+1) -> Bsf */                    \
        gload16(bbase + q * 8 * I_ + ((IT) + 1) * 64, bld + q * 512);          \
      if ((IT) < 6) {                  /* A(it+2) -> freed buffer */           \
        u16* ald = &Asf[cur][wave * 4096];                                     \
        _Pragma("unroll")                                                      \
        for (int q = 0; q < 8; ++q)                                            \
          gload16(Xb + aoff[q] + ((IT) + 2) * 64, ald + q * 512);              \
        asm volatile("s_waitcnt vmcnt(8)" ::: "memory"); /* keep A(it+2) */    \
      } else {                                                                 \
        asm volatile("s_waitcnt vmcnt(0)" ::: "memory"); /* tail drain */      \
      }                                                                        \
      __builtin_amdgcn_s_barrier();    /* staged tiles visible to all */       \
    }                                                                          \
  }

  GSTEP(0) GSTEP(1) GSTEP(2) GSTEP(3) GSTEP(4) GSTEP(5) GSTEP(6) GSTEP(7)
#undef GSTEP

  // epilogue: D row (m) = j = quad*4 + reg -> one float4 per tile
#pragma unroll
  for (int iw = 0; iw < 4; ++iw) {
    const int j0 = n_t * 128 + wj + iw * 16 + quad * 4;
#pragma unroll
    for (int ik = 0; ik < 8; ++ik) {
      const int k0 = m_t * 256 + wk + ik * 16 + ml;
      *(floatx4*)(Y + ((size_t)(be * K_ + k0)) * J_ + j0) = acc[iw][ik];
    }
  }
}

extern "C" void kernel_launch(void* const* d_in, const int* in_sizes, int n_in,
                              void* d_out, int out_size, void* d_ws,
                              size_t ws_size, hipStream_t stream) {
  const float* X  = (const float*)d_in[0];
  const int* ind  = (const int*)d_in[1];
  const float* W  = (const float*)d_in[2];
  float* Y = (float*)d_out;

  u16* Xb = (u16*)d_ws;                                        // 16 MiB
  u16* Wt = (u16*)((char*)d_ws + (size_t)B_ * T_ * I_ * 2);    // + 8 MiB

  prep<<<3072, 256, 0, stream>>>(X, W, Xb, Wt);
  gemm_gather<<<1024, 256, 0, stream>>>(Xb, Wt, ind, Y);
}

// Round 4
// 203.200 us; speedup vs baseline: 1.0931x; 1.0014x over previous
//
#include <hip/hip_runtime.h>

#define B_ 4
#define T_ 4096
#define I_ 512
#define E_ 16
#define K_ 1024
#define J_ 512

typedef unsigned short u16;
typedef unsigned int u32;
typedef __attribute__((ext_vector_type(4))) float floatx4;
typedef __attribute__((ext_vector_type(8))) short short8;
typedef __attribute__((ext_vector_type(4))) u16 u16x4;
typedef __attribute__((ext_vector_type(8))) u16 u16x8;

__device__ __forceinline__ u16 f2bf(float f) {
  unsigned int u = __float_as_uint(f);
  u += 0x7FFFu + ((u >> 16) & 1u);   // round-to-nearest-even
  return (u16)(u >> 16);
}

// async global->LDS, 16B per lane, dest = wave-uniform base + lane*16
__device__ __forceinline__ void gload16(const u16* g, u16* l) {
  __builtin_amdgcn_global_load_lds(
      (const __attribute__((address_space(1))) unsigned int*)(g),
      (__attribute__((address_space(3))) unsigned int*)(l),
      16, 0, 0);
}

// ---- prep (merged): blocks [0,1024) transpose W -> Wt bf16;
//                     blocks [1024,3072) convert X -> Xb bf16 ----------------
__global__ __launch_bounds__(256) void prep(const float* __restrict__ X,
                                            const float* __restrict__ W,
                                            u16* __restrict__ Xb,
                                            u16* __restrict__ Wt) {
  const int tid = threadIdx.x;
  const int blk = blockIdx.x;
  if (blk < 1024) {
    // W[e][i][j] fp32 -> Wt[e][j][i] bf16, 64x64 tiles
    __shared__ u16 tile[64][65];
    const int e  = blk >> 6;
    const int bi = (blk >> 3) & 7;
    const int bj = blk & 7;
    const int i0 = bi * 64, j0 = bj * 64;
#pragma unroll
    for (int p = 0; p < 4; ++p) {
      int r = p * 16 + (tid >> 4);
      int c = (tid & 15) * 4;
      floatx4 v = *(const floatx4*)(W + ((size_t)(e * I_ + i0 + r)) * J_ + j0 + c);
      tile[r][c + 0] = f2bf(v[0]);
      tile[r][c + 1] = f2bf(v[1]);
      tile[r][c + 2] = f2bf(v[2]);
      tile[r][c + 3] = f2bf(v[3]);
    }
    __syncthreads();
#pragma unroll
    for (int p = 0; p < 2; ++p) {
      int j = p * 32 + (tid >> 3);
      int ch = tid & 7;
      u16x8 o;
#pragma unroll
      for (int s = 0; s < 8; ++s) o[s] = tile[ch * 8 + s][j];
      *(u16x8*)(Wt + ((size_t)(e * J_ + j0 + j)) * I_ + i0 + ch * 8) = o;
    }
  } else {
    const int n4 = B_ * T_ * I_ / 4;
    int i = (blk - 1024) * 256 + tid;
    const int stride = 2048 * 256;
    for (; i < n4; i += stride) {
      floatx4 v = ((const floatx4*)X)[i];
      u16x4 o;
      o[0] = f2bf(v[0]); o[1] = f2bf(v[1]); o[2] = f2bf(v[2]); o[3] = f2bf(v[3]);
      ((u16x4*)Xb)[i] = o;
    }
  }
}

// ---- main: gather + bf16 MFMA GEMM -----------------------------------------
// Round-3 structure (kept): per block 256 K-rows x 128 J-cols of one (b,e);
// 4 waves as 2x2 of 128K x 64J wave-tiles; acc 4(j) x 8(k); BK=64, 8 K-steps.
// A (gathered rows) double-buffered 2x32KB, B (Wt) single 16KB -> 80KB LDS
// = exactly 2 blocks/CU. Per step: compute(A[cur],B) ; barrier ; issue
// B(it+1) [4 contig] + A(it+2) [8 gathers, into freed buffer] ;
// s_waitcnt vmcnt(8) (A(it+2) stays in flight) ; barrier.
// Round-4 change: T5 s_setprio(1) around the MFMA cluster. This schedule is
// now counted-vmcnt phase-split (the regime where T5 pays per m218b/m224:
// waves across the 2 co-resident blocks are desynced; some issue gathers
// while others run MFMA -> priority arbitration favors the matrix pipe).
// MFMA roles: A-op = Wt rows (M=J), B-op = gathered X rows (N=K) so D rows
// are consecutive j -> dwordx4 stores. XOR chunk swizzle c_lds = c ^ (row&7).
__global__ __launch_bounds__(256, 2) void gemm_gather(
    const u16* __restrict__ Xb, const u16* __restrict__ Wt,
    const int* __restrict__ ind, float* __restrict__ Y) {
  __shared__ alignas(16) u16 Asf[2][256 * 64];   // gathered X rows: 2 x 32 KB
  __shared__ alignas(16) u16 Bsf[128 * 64];      // Wt rows:             16 KB

  const int tid = threadIdx.x;
  // XCD swizzle: grid 1024 = 8 XCDs x 128-chunk. Within a chunk all 16
  // blocks of each be (4 m_t x 4 n_t) co-reside on one XCD: the 4
  // n_t-siblings gather IDENTICAL rows (ind is n_t-independent) -> L2 hits.
  const int blk = ((int)blockIdx.x & 7) * 128 + ((int)blockIdx.x >> 3);
  const int m_t = blk & 3;             // K tile
  const int n_t = (blk >> 2) & 3;      // J tile
  const int be  = blk >> 4;            // b*E + e
  const int e = be & 15;
  const int b = be >> 4;

  const int lane = tid & 63;
  const int wave = tid >> 6;

  // staging mapping: one gload16 covers 8 rows x 8 chunks (16B each)
  const int lr = lane >> 3;                  // row within octet
  const int cg = (lane & 7) ^ lr;            // global chunk for this lane

  // A: 64 gathered rows per wave (8 instrs); keep 32-bit element offsets
  u32 aoff[8];
#pragma unroll
  for (int q = 0; q < 8; ++q) {
    const int r = wave * 64 + q * 8 + lr;
    const int t = ind[be * K_ + m_t * 256 + r];
    aoff[q] = (u32)(b * T_ + t) * I_ + cg * 8;
  }
  // B: 32 rows per wave (4 instrs), contiguous base
  const u16* bbase =
      Wt + ((size_t)(e * J_ + n_t * 128 + wave * 32 + lr)) * I_ + cg * 8;
  u16* bld = Bsf + (wave * 32) * 64;

  const int wj = (wave & 1) * 64;      // J offset of wave-tile
  const int wk = (wave >> 1) * 128;    // K offset of wave-tile
  const int ml = lane & 15;
  const int quad = lane >> 4;

  floatx4 acc[4][8] = {};              // [iw = J blocks][ik = K blocks]

  // ---- prologue: B(0), A(0) into buf0, A(1) into buf1; wait all but A(1) --
#pragma unroll
  for (int q = 0; q < 4; ++q) gload16(bbase + q * 8 * I_, bld + q * 512);
  {
    u16* a0 = &Asf[0][wave * 4096];
#pragma unroll
    for (int q = 0; q < 8; ++q) gload16(Xb + aoff[q], a0 + q * 512);
    u16* a1 = &Asf[1][wave * 4096];
#pragma unroll
    for (int q = 0; q < 8; ++q) gload16(Xb + aoff[q] + 64, a1 + q * 512);
  }
  asm volatile("s_waitcnt vmcnt(8)" ::: "memory");   // B0 + A0 done
  __builtin_amdgcn_s_barrier();

#define GSTEP(IT)                                                              \
  {                                                                            \
    constexpr int cur = (IT) & 1;                                              \
    __builtin_amdgcn_s_setprio(1);                                             \
    _Pragma("unroll")                                                          \
    for (int s = 0; s < 2; ++s) {      /* two K=32 sub-steps */                \
      const int c = s * 4 + quad;                                              \
      short8 wf[4];                                                            \
      _Pragma("unroll")                                                        \
      for (int i = 0; i < 4; ++i) {                                            \
        const int jr = wj + i * 16 + ml;                                       \
        wf[i] = *(const short8*)&Bsf[jr * 64 + ((c ^ (jr & 7)) * 8)];          \
      }                                                                        \
      _Pragma("unroll")                                                        \
      for (int ik = 0; ik < 8; ++ik) {                                         \
        const int kr = wk + ik * 16 + ml;                                      \
        const short8 xf =                                                      \
            *(const short8*)&Asf[cur][kr * 64 + ((c ^ (kr & 7)) * 8)];         \
        _Pragma("unroll")                                                      \
        for (int iw = 0; iw < 4; ++iw)                                         \
          acc[iw][ik] = __builtin_amdgcn_mfma_f32_16x16x32_bf16(               \
              wf[iw], xf, acc[iw][ik], 0, 0, 0);                               \
      }                                                                        \
    }                                                                          \
    __builtin_amdgcn_s_setprio(0);                                             \
    if ((IT) < 7) {                                                            \
      __builtin_amdgcn_s_barrier();    /* all waves done reading Bsf/A[cur] */ \
      _Pragma("unroll")                                                        \
      for (int q = 0; q < 4; ++q)      /* B(it+1) -> Bsf */                    \
        gload16(bbase + q * 8 * I_ + ((IT) + 1) * 64, bld + q * 512);          \
      if ((IT) < 6) {                  /* A(it+2) -> freed buffer */           \
        u16* ald = &Asf[cur][wave * 4096];                                     \
        _Pragma("unroll")                                                      \
        for (int q = 0; q < 8; ++q)                                            \
          gload16(Xb + aoff[q] + ((IT) + 2) * 64, ald + q * 512);              \
        asm volatile("s_waitcnt vmcnt(8)" ::: "memory"); /* keep A(it+2) */    \
      } else {                                                                 \
        asm volatile("s_waitcnt vmcnt(0)" ::: "memory"); /* tail drain */      \
      }                                                                        \
      __builtin_amdgcn_s_barrier();    /* staged tiles visible to all */       \
    }                                                                          \
  }

  GSTEP(0) GSTEP(1) GSTEP(2) GSTEP(3) GSTEP(4) GSTEP(5) GSTEP(6) GSTEP(7)
#undef GSTEP

  // epilogue: D row (m) = j = quad*4 + reg -> one float4 per tile
#pragma unroll
  for (int iw = 0; iw < 4; ++iw) {
    const int j0 = n_t * 128 + wj + iw * 16 + quad * 4;
#pragma unroll
    for (int ik = 0; ik < 8; ++ik) {
      const int k0 = m_t * 256 + wk + ik * 16 + ml;
      *(floatx4*)(Y + ((size_t)(be * K_ + k0)) * J_ + j0) = acc[iw][ik];
    }
  }
}

extern "C" void kernel_launch(void* const* d_in, const int* in_sizes, int n_in,
                              void* d_out, int out_size, void* d_ws,
                              size_t ws_size, hipStream_t stream) {
  const float* X  = (const float*)d_in[0];
  const int* ind  = (const int*)d_in[1];
  const float* W  = (const float*)d_in[2];
  float* Y = (float*)d_out;

  u16* Xb = (u16*)d_ws;                                        // 16 MiB
  u16* Wt = (u16*)((char*)d_ws + (size_t)B_ * T_ * I_ * 2);    // + 8 MiB

  prep<<<3072, 256, 0, stream>>>(X, W, Xb, Wt);
  gemm_gather<<<1024, 256, 0, stream>>>(Xb, Wt, ind, Y);
}